// Round 4
// baseline (161.496 us; speedup 1.0000x reference)
//
#include <hip/hip_runtime.h>
#include <hip/hip_fp16.h>

#define HIDDEN 768
#define HEADS 12
#define HDIM 64
#define SEQ 2048
#define BATCH 4
#define ORDER 5
#define LOG2E 1.44269504088896f

typedef _Float16 f16;
typedef _Float16 f16x8 __attribute__((ext_vector_type(8)));
typedef _Float16 f16x4 __attribute__((ext_vector_type(4)));
typedef float f32x4 __attribute__((ext_vector_type(4)));

#define MFMA16x16x32(A, B, C) __builtin_amdgcn_mfma_f32_16x16x32_f16(A, B, C, 0, 0, 0)

#define GLD16(gptr, lptr)                                                     \
    __builtin_amdgcn_global_load_lds(                                         \
        (const __attribute__((address_space(1))) void*)(gptr),                \
        (__attribute__((address_space(3))) void*)(lptr), 16, 0, 0)

// ---------------------------------------------------------------------------
// Kernel 1: prep. (a) convert X -> Xh f16, Wq/Wk/Wv -> Wh[2304][768] f16;
// (b) Chebyshev bias table (x LOG2E).
// ---------------------------------------------------------------------------
#define NXG (8192 * 768 / 8)
#define NWG (768 * 768 / 8)
#define NCVT (NXG + 3 * NWG)
#define NBIAS (HEADS * (2 * SEQ - 1))

__global__ __launch_bounds__(256)
void prep_kernel(const float* __restrict__ X,
                 const float* __restrict__ Wq, const float* __restrict__ Wk,
                 const float* __restrict__ Wv, const float* __restrict__ alphas,
                 f16* __restrict__ Xh, f16* __restrict__ Wh,
                 float* __restrict__ biasTab)
{
    const int tid = blockIdx.x * 256 + threadIdx.x;
    if (tid < NCVT) {
        const float* src;
        f16* dst;
        size_t off;
        if (tid < NXG)               { src = X;  dst = Xh;              off = (size_t)tid * 8; }
        else if (tid < NXG + NWG)    { src = Wq; dst = Wh;              off = (size_t)(tid - NXG) * 8; }
        else if (tid < NXG + 2*NWG)  { src = Wk; dst = Wh + 768 * 768;  off = (size_t)(tid - NXG - NWG) * 8; }
        else                         { src = Wv; dst = Wh + 2*768*768;  off = (size_t)(tid - NXG - 2*NWG) * 8; }
        float4 a = *(const float4*)(src + off);
        float4 b = *(const float4*)(src + off + 4);
        f16x8 h;
        h[0] = (f16)a.x; h[1] = (f16)a.y; h[2] = (f16)a.z; h[3] = (f16)a.w;
        h[4] = (f16)b.x; h[5] = (f16)b.y; h[6] = (f16)b.z; h[7] = (f16)b.w;
        *(f16x8*)(dst + off) = h;
    } else {
        int idx = tid - NCVT;
        if (idx >= NBIAS) return;
        const int W = 2 * SEQ - 1;
        int h = idx / W;
        int t = idx - h * W;
        float x = (float)(t - (SEQ - 1)) / (float)(SEQ - 1);
        float tp = 1.0f;
        float tc = x;
        float acc = alphas[h * (ORDER + 1) + 0] * tp + alphas[h * (ORDER + 1) + 1] * tc;
#pragma unroll
        for (int k = 2; k <= ORDER; ++k) {
            float tn = 2.0f * x * tc - tp;
            acc += alphas[h * (ORDER + 1) + k] * tn;
            tp = tc; tc = tn;
        }
        biasTab[idx] = acc * LOG2E;
    }
}

// ---------------------------------------------------------------------------
// Kernel 2: fused QKV GEMM, m97 structure (global_load_lds w16, BK=32).
// ---------------------------------------------------------------------------
__global__ __launch_bounds__(256)
void qkv_kernel(const f16* __restrict__ Xh, const f16* __restrict__ Wh,
                const float* __restrict__ bq, const float* __restrict__ bk,
                const float* __restrict__ bv,
                f16* __restrict__ qf, f16* __restrict__ kf, f16* __restrict__ vtf)
{
    const int wgid = (blockIdx.x & 7) * 144 + (blockIdx.x >> 3);
    const int tileM = wgid / 18;
    const int tileN = wgid % 18;
    const int m0 = tileM * 128;
    const int n0g = tileN * 128;
    const int w = tileN / 6;
    const int nloc0 = n0g - w * 768;
    const float* __restrict__ bias = (w == 0) ? bq : (w == 1) ? bk : bv;

    __shared__ __align__(16) f16 sA[128][32];
    __shared__ __align__(16) f16 sB[128][32];

    const int t = threadIdx.x;
    const int lane = t & 63;
    const int wv = t >> 6;
    const int wm = wv >> 1, wn = wv & 1;
    const int fr = lane & 15;
    const int kg = lane >> 4;

    const int srow = lane >> 2;
    const int scol = (lane & 3) * 8;

    f32x4 acc[4][4];
#pragma unroll
    for (int i = 0; i < 4; ++i)
#pragma unroll
        for (int j = 0; j < 4; ++j) acc[i][j] = (f32x4)(0.0f);

    const f16* gA = Xh + (size_t)(m0 + wv * 32 + srow) * 768 + scol;
    const f16* gB = Wh + (size_t)(n0g + wv * 32 + srow) * 768 + scol;
    f16* lA0 = &sA[wv * 32][0];
    f16* lA1 = &sA[wv * 32 + 16][0];
    f16* lB0 = &sB[wv * 32][0];
    f16* lB1 = &sB[wv * 32 + 16][0];

    for (int kt = 0; kt < 768; kt += 32) {
        __syncthreads();
        GLD16(gA + kt, lA0);
        GLD16(gA + kt + 16 * 768, lA1);
        GLD16(gB + kt, lB0);
        GLD16(gB + kt + 16 * 768, lB1);
        __syncthreads();

        f16x8 af[4], bf[4];
#pragma unroll
        for (int i = 0; i < 4; ++i) {
            af[i] = *(const f16x8*)&sA[wm * 64 + i * 16 + fr][kg * 8];
            bf[i] = *(const f16x8*)&sB[wn * 64 + i * 16 + fr][kg * 8];
        }
#pragma unroll
        for (int mi = 0; mi < 4; ++mi)
#pragma unroll
            for (int ni = 0; ni < 4; ++ni)
                acc[mi][ni] = MFMA16x16x32(af[mi], bf[ni], acc[mi][ni]);
    }

    const int bb = m0 >> 11;
#pragma unroll
    for (int mi = 0; mi < 4; ++mi) {
        const int s0 = (m0 & 2047) + wm * 64 + mi * 16 + kg * 4;
#pragma unroll
        for (int ni = 0; ni < 4; ++ni) {
            const int nloc = nloc0 + wn * 64 + ni * 16 + fr;
            const int hh = nloc >> 6, d = nloc & 63;
            const size_t bh = (size_t)bb * HEADS + hh;
            const float bc = bias[nloc];
            if (w == 2) {
                f16x4 pv;
#pragma unroll
                for (int r = 0; r < 4; ++r) pv[r] = (f16)(acc[mi][ni][r] + bc);
                *(f16x4*)&vtf[(bh * HDIM + d) * SEQ + s0] = pv;
            } else if (w == 0) {
#pragma unroll
                for (int r = 0; r < 4; ++r)
                    qf[(bh * SEQ + s0 + r) * HDIM + d] =
                        (f16)((acc[mi][ni][r] + bc) * (0.125f * LOG2E));
            } else {
#pragma unroll
                for (int r = 0; r < 4; ++r)
                    kf[(bh * SEQ + s0 + r) * HDIM + d] = (f16)(acc[mi][ni][r] + bc);
            }
        }
    }
}

// ---------------------------------------------------------------------------
// Kernel 3: flash attention. XCD-affine grid, GLD16 dbuf K/VT staging with
// source-side XOR chunk swizzle, 1 barrier per 64-key tile, no-max softmax.
// ---------------------------------------------------------------------------
struct __align__(16) SMem {
    union {
        f16 kv[2][2][64][64];   // [buf][0=K,1=VT][row][col], 16B-chunk swizzled
        float sO[4][16][72];    // epilogue transpose, per-wave
    } u;                        // 32 KB
    f16 sP[4][32][64];          // per-wave P [q][key], chunk swizzled, 16 KB
    f16 sBiasH[2304];           // bias*LOG2E as f16, 4.5 KB
};

__global__ __launch_bounds__(256, 3)
void attn_kernel(const f16* __restrict__ qf, const f16* __restrict__ kf,
                 const f16* __restrict__ vtf, const float* __restrict__ biasTab,
                 float* __restrict__ out)
{
    // XCD-affine: all 16 q-tiles of one (b,h) land on one XCD (blockIdx%8).
    const int xcd = blockIdx.x & 7;
    const int ii = blockIdx.x >> 3;
    const int qt = ii & 15;
    const int bh = (ii >> 4) * 8 + xcd;     // 0..47, bijective
    const int h = bh % HEADS;
    const int b = bh / HEADS;
    const int q0 = qt * 128;

    __shared__ SMem sm;

    const int t = threadIdx.x;
    const int lane = t & 63;
    const int wv = t >> 6;
    const int fr = lane & 15;
    const int kg = lane >> 4;
    const int r7 = fr & 7;

    // Stage bias slice as f16: sBiasH[u] = biasTab[h*4095 + u + 1920 - q0]
    {
        const float* bsrc = biasTab + (size_t)h * (2 * SEQ - 1) + 1920 - q0;
        for (int u = t; u < 2175; u += 256) sm.sBiasH[u] = (f16)bsrc[u];
    }

    // Q fragments in registers
    f16x8 aq[2][2];
#pragma unroll
    for (int s = 0; s < 2; ++s)
#pragma unroll
        for (int c = 0; c < 2; ++c)
            aq[s][c] = *(const f16x8*)(qf +
                ((size_t)bh * SEQ + q0 + wv * 32 + s * 16 + fr) * HDIM + c * 32 + kg * 8);

    // Async stage of one 64-key tile into buf: linear LDS dest, XOR-swizzled
    // global source (chunk' = chunk ^ (row&7)); wave wv covers rows wv*16..+15.
    auto stage = [&](int buf, int j0) {
        const int lrow = lane >> 3;          // 0..7
        const int sw = 8 * ((lane & 7) ^ lrow);
        const f16* gk = kf + ((size_t)bh * SEQ + j0 + wv * 16 + lrow) * HDIM + sw;
        GLD16(gk,            &sm.u.kv[buf][0][wv * 16][0]);
        GLD16(gk + 8 * HDIM, &sm.u.kv[buf][0][wv * 16 + 8][0]);
        const f16* gv = vtf + ((size_t)bh * HDIM + wv * 16 + lrow) * SEQ + j0 + sw;
        GLD16(gv,           &sm.u.kv[buf][1][wv * 16][0]);
        GLD16(gv + 8 * SEQ, &sm.u.kv[buf][1][wv * 16 + 8][0]);
    };

    f32x4 oacc[2][4];
    float lsum[2] = {0.0f, 0.0f};
#pragma unroll
    for (int s = 0; s < 2; ++s)
#pragma unroll
        for (int df = 0; df < 4; ++df) oacc[s][df] = (f32x4)(0.0f);

    int cur = 0;
    stage(0, 0);

    for (int j0 = 0; j0 < SEQ; j0 += 64) {
        __syncthreads();   // buf[cur] landed; all waves done with buf[cur^1]
        if (j0 + 64 < SEQ) stage(cur ^ 1, j0 + 64);

        // T[key][q] = K Q^T
        f32x4 tt[2][4];
#pragma unroll
        for (int s = 0; s < 2; ++s)
#pragma unroll
            for (int ni = 0; ni < 4; ++ni) tt[s][ni] = (f32x4)(0.0f);
#pragma unroll
        for (int ni = 0; ni < 4; ++ni) {
            const f16* kb = &sm.u.kv[cur][0][ni * 16 + fr][0];
            f16x8 bk0 = *(const f16x8*)(kb + 8 * (kg ^ r7));
            f16x8 bk1 = *(const f16x8*)(kb + 8 * ((kg + 4) ^ r7));
            tt[0][ni] = MFMA16x16x32(bk0, aq[0][0], tt[0][ni]);
            tt[0][ni] = MFMA16x16x32(bk1, aq[0][1], tt[0][ni]);
            tt[1][ni] = MFMA16x16x32(bk0, aq[1][0], tt[1][ni]);
            tt[1][ni] = MFMA16x16x32(bk1, aq[1][1], tt[1][ni]);
        }

        // bias prefetch: element (s,ni,r): key=j0+ni*16+kg*4+r, q=wv*32+s*16+fr
        const int ub = j0 + kg * 4 - wv * 32 - fr + 127;
        float bb[5][4];
#pragma unroll
        for (int g = 0; g < 5; ++g)
#pragma unroll
            for (int r = 0; r < 4; ++r)
                bb[g][r] = (float)sm.sBiasH[ub + (g - 1) * 16 + r];

        // softmax (no max subtraction) + P -> LDS (swizzled, wave-private)
#pragma unroll
        for (int s = 0; s < 2; ++s) {
            float ls = 0.0f;
#pragma unroll
            for (int ni = 0; ni < 4; ++ni) {
                f16x4 ph;
#pragma unroll
                for (int r = 0; r < 4; ++r) {
                    float p = __builtin_amdgcn_exp2f(tt[s][ni][r] + bb[ni - s + 1][r]);
                    ls += p;
                    ph[r] = (f16)p;
                }
                *(f16x4*)&sm.sP[wv][s * 16 + fr]
                    [(((ni * 2 + (kg >> 1)) ^ r7) * 8) + (kg & 1) * 4] = ph;
            }
            lsum[s] += ls;
        }

        // PV: O^T[d][q] += MFMA(VT rows, P rows)
        const f16* pb0 = &sm.sP[wv][fr][0];
        const f16* pb1 = &sm.sP[wv][16 + fr][0];
        f16x8 ap00 = *(const f16x8*)(pb0 + 8 * (kg ^ r7));
        f16x8 ap01 = *(const f16x8*)(pb0 + 8 * ((kg + 4) ^ r7));
        f16x8 ap10 = *(const f16x8*)(pb1 + 8 * (kg ^ r7));
        f16x8 ap11 = *(const f16x8*)(pb1 + 8 * ((kg + 4) ^ r7));
#pragma unroll
        for (int df = 0; df < 4; ++df) {
            const f16* vb = &sm.u.kv[cur][1][df * 16 + fr][0];
            f16x8 bv0 = *(const f16x8*)(vb + 8 * (kg ^ r7));
            f16x8 bv1 = *(const f16x8*)(vb + 8 * ((kg + 4) ^ r7));
            oacc[0][df] = MFMA16x16x32(bv0, ap00, oacc[0][df]);
            oacc[0][df] = MFMA16x16x32(bv1, ap01, oacc[0][df]);
            oacc[1][df] = MFMA16x16x32(bv0, ap10, oacc[1][df]);
            oacc[1][df] = MFMA16x16x32(bv1, ap11, oacc[1][df]);
        }
        cur ^= 1;
    }

    float inv[2];
#pragma unroll
    for (int s = 0; s < 2; ++s) {
        float l = lsum[s];
        l += __shfl_xor(l, 16, 64);
        l += __shfl_xor(l, 32, 64);
        inv[s] = 1.0f / l;
    }

    __syncthreads();   // all PV reads of kv done before reuse as sO
#pragma unroll
    for (int s = 0; s < 2; ++s) {
#pragma unroll
        for (int df = 0; df < 4; ++df) {
            f32x4 v = oacc[s][df];
            v *= inv[s];
            *(f32x4*)&sm.u.sO[wv][fr][df * 16 + kg * 4] = v;
        }
        int row = lane >> 2;
        int cb = (lane & 3) * 16;
        float* dst = out + ((size_t)b * SEQ + q0 + wv * 32 + s * 16 + row) * HIDDEN
                         + h * HDIM + cb;
#pragma unroll
        for (int i = 0; i < 4; ++i) {
            f32x4 v = *(const f32x4*)&sm.u.sO[wv][row][cb + 4 * i];
            *(f32x4*)(dst + 4 * i) = v;
        }
        __syncthreads();   // sO region reused for s=1
    }
}

// ---------------------------------------------------------------------------
extern "C" void kernel_launch(void* const* d_in, const int* in_sizes, int n_in,
                              void* d_out, int out_size, void* d_ws, size_t ws_size,
                              hipStream_t stream) {
    const float* X      = (const float*)d_in[0];
    const float* Wq     = (const float*)d_in[1];
    const float* bq     = (const float*)d_in[2];
    const float* Wk     = (const float*)d_in[3];
    const float* bk     = (const float*)d_in[4];
    const float* Wv     = (const float*)d_in[5];
    const float* bv     = (const float*)d_in[6];
    const float* alphas = (const float*)d_in[7];
    float* out = (float*)d_out;

    const size_t nQ = (size_t)BATCH * HEADS * SEQ * HDIM;
    f16* qf  = (f16*)d_ws;
    f16* kf  = qf + nQ;
    f16* vtf = kf + nQ;
    float* biasTab = (float*)(vtf + nQ);
    f16* Xh = (f16*)(biasTab + 49152);
    f16* Wh = Xh + (size_t)8192 * 768;

    const int prep_threads = NCVT + NBIAS;
    hipLaunchKernelGGL(prep_kernel, dim3((prep_threads + 255) / 256), dim3(256), 0,
                       stream, X, Wq, Wk, Wv, alphas, Xh, Wh, biasTab);
    hipLaunchKernelGGL(qkv_kernel, dim3(1152), dim3(256), 0, stream,
                       Xh, Wh, bq, bk, bv, qf, kf, vtf);
    hipLaunchKernelGGL(attn_kernel, dim3(BATCH * HEADS * 16), dim3(256), 0, stream,
                       qf, kf, vtf, biasTab, out);
}